// Round 1
// baseline (455.454 us; speedup 1.0000x reference)
//
#include <hip/hip_runtime.h>
#include <hip/hip_bf16.h>
#include <math.h>

// ---------------------------------------------------------------------------
// DistributedMoE forward, MI355X.
// Key algorithmic win: each sample is dispatched to exactly ONE expert
// (capacity scan picks a single chosen[b]; softmax over one element == 1),
// so experts run only on their assigned samples: 8x less conv work than the
// reference vmap-over-all-experts graph.
//
// out layout (fp32): final[256,10] @0, balanced[256,8] @2560, D[256,8] @4608
// ws layout: trunkfeat f32[256*128] @0, tk i32[512] @131072B, chosen i32[256]
// ---------------------------------------------------------------------------

#define BN_RS_EXPR (1.0f / sqrtf(1.00001f))

// ======================= trunk: conv1+conv2+pool+avg =======================
// grid 1024 = 256 samples x 4 quadrants, 128 threads
__global__ __launch_bounds__(128) void trunk_kernel(
    const float* __restrict__ x, const float* __restrict__ tw1,
    const float* __restrict__ tg1, const float* __restrict__ tb1,
    const float* __restrict__ tw2, const float* __restrict__ tg2,
    const float* __restrict__ tb2, float* __restrict__ tf)
{
  __shared__ __align__(16) float sx[1200];     // x tile [3][20][20]
  __shared__ __align__(16) float sa1[11520];   // conv1 out [32][18][20] (halo incl.)
  __shared__ __align__(16) float sw1[864];
  __shared__ __align__(16) float swB[1152];    // w2 chunk [4ic][9][32oc]
  __shared__ float s1[32], o1[32], s2[32], o2[32];

  const int t = threadIdx.x;
  const int b = blockIdx.x >> 2, q = blockIdx.x & 3;
  const int qy = q >> 1, qx = q & 1;
  const int y0 = qy * 16, x0 = qx * 16;
  const float rs = BN_RS_EXPR;

  for (int j = t; j < 1200; j += 128) {
    int ic = j / 400, r = j % 400, yy = r / 20, xx = r % 20;
    int gy = y0 - 2 + yy, gx = x0 - 2 + xx;
    float v = 0.f;
    if (gy >= 0 && gy < 32 && gx >= 0 && gx < 32) v = x[b*3072 + ic*1024 + gy*32 + gx];
    sx[j] = v;
  }
  for (int j = t; j < 864; j += 128) sw1[j] = tw1[j];
  if (t < 32) { s1[t] = tg1[t]*rs; o1[t] = tb1[t]; s2[t] = tg2[t]*rs; o2[t] = tb2[t]; }
  __syncthreads();

  // conv1 -> sa1; row item = (oc, r), r in [0,18) covers local rows -1..16
  for (int it = 0; it < 5; ++it) {
    const int item = it*128 + t;
    if (item >= 576) break;
    const int oc = item / 18, r = item % 18;
    const int gy = y0 - 1 + r;
    float acc[18];
    #pragma unroll
    for (int c2 = 0; c2 < 18; ++c2) acc[c2] = 0.f;
    if (gy >= 0 && gy < 32) {
      for (int ic = 0; ic < 3; ++ic) {
        float w[9];
        #pragma unroll
        for (int k = 0; k < 9; ++k) w[k] = sw1[oc*27 + ic*9 + k];
        #pragma unroll
        for (int wr = 0; wr < 3; ++wr) {
          float rv[20];
          const float4* rp = (const float4*)&sx[ic*400 + (r + wr)*20];
          #pragma unroll
          for (int j4 = 0; j4 < 5; ++j4) {
            float4 v4 = rp[j4];
            rv[4*j4] = v4.x; rv[4*j4+1] = v4.y; rv[4*j4+2] = v4.z; rv[4*j4+3] = v4.w;
          }
          #pragma unroll
          for (int c2 = 0; c2 < 18; ++c2)
            #pragma unroll
            for (int kx = 0; kx < 3; ++kx)
              acc[c2] = fmaf(w[wr*3 + kx], rv[c2 + kx], acc[c2]);
        }
      }
    }
    const float s = s1[oc], bo = o1[oc];
    #pragma unroll
    for (int c2 = 0; c2 < 18; ++c2) {
      const int gx = x0 - 1 + c2;
      float v = 0.f;  // out-of-image conv1 outputs act as conv2 zero padding
      if (gy >= 0 && gy < 32 && gx >= 0 && gx < 32) v = fmaxf(fmaf(acc[c2], s, bo), 0.f);
      sa1[oc*360 + r*20 + c2] = v;
    }
  }

  // conv2: thread = (ocg(8)x4oc, pr(8)=pooled row, ch(2)=col half)
  const int ocg = t >> 4, pr = (t >> 1) & 7, ch = t & 1;
  float acc[4][2][8];
  #pragma unroll
  for (int o = 0; o < 4; ++o)
    #pragma unroll
    for (int dy = 0; dy < 2; ++dy)
      #pragma unroll
      for (int xx2 = 0; xx2 < 8; ++xx2) acc[o][dy][xx2] = 0.f;

  for (int c = 0; c < 8; ++c) {
    __syncthreads();
    for (int j = t; j < 1152; j += 128) {
      int icl = j / 288, r = j % 288, k = r / 32, oc = r % 32;
      swB[j] = tw2[oc*288 + (4*c + icl)*9 + k];
    }
    __syncthreads();
    #pragma unroll
    for (int icl = 0; icl < 4; ++icl) {
      const int ic = 4*c + icl;
      float w[4][9];
      #pragma unroll
      for (int k = 0; k < 9; ++k) {
        float4 wv = *(const float4*)&swB[icl*288 + k*32 + 4*ocg];
        w[0][k] = wv.x; w[1][k] = wv.y; w[2][k] = wv.z; w[3][k] = wv.w;
      }
      #pragma unroll
      for (int wr = 0; wr < 4; ++wr) {   // sa1 row = 2*pr + wr, always in [0,18)
        float rv[10];
        const float2* rp = (const float2*)&sa1[ic*360 + (2*pr + wr)*20 + 8*ch];
        #pragma unroll
        for (int j2 = 0; j2 < 5; ++j2) { float2 v2 = rp[j2]; rv[2*j2] = v2.x; rv[2*j2+1] = v2.y; }
        #pragma unroll
        for (int dy = 0; dy < 2; ++dy) {
          const int ky = wr - dy;
          if (ky < 0 || ky > 2) continue;
          #pragma unroll
          for (int xx2 = 0; xx2 < 8; ++xx2)
            #pragma unroll
            for (int kx = 0; kx < 3; ++kx) {
              const float iv = rv[xx2 + kx];
              #pragma unroll
              for (int o = 0; o < 4; ++o)
                acc[o][dy][xx2] = fmaf(w[o][ky*3 + kx], iv, acc[o][dy][xx2]);
            }
        }
      }
    }
  }

  // bn + relu + maxpool2 + quadrant average (8x8 pooled -> 1), per oc
  #pragma unroll
  for (int o = 0; o < 4; ++o) {
    const int oc = 4*ocg + o;
    const float s = s2[oc], bo = o2[oc];
    float gp = 0.f;
    #pragma unroll
    for (int pc = 0; pc < 4; ++pc) {
      float v0 = fmaxf(fmaf(acc[o][0][2*pc],   s, bo), 0.f);
      float v1 = fmaxf(fmaf(acc[o][0][2*pc+1], s, bo), 0.f);
      float v2 = fmaxf(fmaf(acc[o][1][2*pc],   s, bo), 0.f);
      float v3 = fmaxf(fmaf(acc[o][1][2*pc+1], s, bo), 0.f);
      gp += fmaxf(fmaxf(v0, v1), fmaxf(v2, v3));
    }
    gp += __shfl_xor(gp, 1);
    gp += __shfl_xor(gp, 2);
    gp += __shfl_xor(gp, 4);
    gp += __shfl_xor(gp, 8);
    if ((t & 15) == 0) tf[b*128 + oc*4 + qy*2 + qx] = gp * (1.f/64.f);
  }
}

// ============================== gate + top2 ================================
__global__ __launch_bounds__(64) void gate_kernel(
    const float* __restrict__ tf, const float* __restrict__ tfw, const float* __restrict__ tfb,
    const float* __restrict__ gw1, const float* __restrict__ gb1,
    const float* __restrict__ gw2, const float* __restrict__ gb2,
    float* __restrict__ outBal, int* __restrict__ tk)
{
  __shared__ float feat[128], rf[64], g1[32], bal[8];
  const int b = blockIdx.x, t = threadIdx.x;
  feat[t] = tf[b*128 + t];
  feat[64 + t] = tf[b*128 + 64 + t];
  __syncthreads();
  {
    float a = tfb[t];
    const float4* wp = (const float4*)&tfw[t*128];
    #pragma unroll 8
    for (int i4 = 0; i4 < 32; ++i4) {
      float4 wv = wp[i4];
      a = fmaf(wv.x, feat[4*i4], a);   a = fmaf(wv.y, feat[4*i4+1], a);
      a = fmaf(wv.z, feat[4*i4+2], a); a = fmaf(wv.w, feat[4*i4+3], a);
    }
    rf[t] = fmaxf(a, 0.f);
  }
  __syncthreads();
  if (t < 32) {
    float a = gb1[t];
    const float4* wp = (const float4*)&gw1[t*64];
    #pragma unroll
    for (int i4 = 0; i4 < 16; ++i4) {
      float4 wv = wp[i4];
      a = fmaf(wv.x, rf[4*i4], a);   a = fmaf(wv.y, rf[4*i4+1], a);
      a = fmaf(wv.z, rf[4*i4+2], a); a = fmaf(wv.w, rf[4*i4+3], a);
    }
    g1[t] = fmaxf(a, 0.f);
  }
  __syncthreads();
  if (t < 8) {
    float a = gb2[t];
    const float4* wp = (const float4*)&gw2[t*32];
    #pragma unroll
    for (int i4 = 0; i4 < 8; ++i4) {
      float4 wv = wp[i4];
      a = fmaf(wv.x, g1[4*i4], a);   a = fmaf(wv.y, g1[4*i4+1], a);
      a = fmaf(wv.z, g1[4*i4+2], a); a = fmaf(wv.w, g1[4*i4+3], a);
    }
    // usage = 1/8 > MIN_USE -> boost = 0; balanced = scores - LOAD_PEN/8 = s - 0.25
    const float v = a - 0.25f;
    bal[t] = v;
    outBal[b*8 + t] = v;
  }
  __syncthreads();
  if (t == 0) {
    int t0 = 0; float b0 = bal[0];
    #pragma unroll
    for (int e2 = 1; e2 < 8; ++e2) if (bal[e2] > b0) { b0 = bal[e2]; t0 = e2; }
    int t1 = -1; float b1 = -3.4e38f;
    #pragma unroll
    for (int e2 = 0; e2 < 8; ++e2) if (e2 != t0 && bal[e2] > b1) { b1 = bal[e2]; t1 = e2; }
    tk[b*2] = t0; tk[b*2 + 1] = t1;
  }
}

// =================== serial capacity-constrained routing ===================
__global__ __launch_bounds__(256) void route_kernel(const int* __restrict__ tk,
                                                    int* __restrict__ chosen,
                                                    float* __restrict__ outD)
{
  __shared__ int stk[512];
  __shared__ int sch[256];
  const int t = threadIdx.x;
  stk[t] = tk[t]; stk[256 + t] = tk[256 + t];
  __syncthreads();
  if (t == 0) {
    float L0=0,L1=0,L2=0,L3=0,L4=0,L5=0,L6=0,L7=0;   // expert loads in registers
    for (int i = 0; i < 256; ++i) {
      const int a = stk[2*i], c = stk[2*i+1];
      const float la = (a==0)?L0:(a==1)?L1:(a==2)?L2:(a==3)?L3:(a==4)?L4:(a==5)?L5:(a==6)?L6:L7;
      const float lc = (c==0)?L0:(c==1)?L1:(c==2)?L2:(c==3)?L3:(c==4)?L4:(c==5)?L5:(c==6)?L6:L7;
      // jax: idx = any(avail) ? argmax(avail) : argmin(lt); first-index ties
      const int ch = (la < 48.f) ? a : ((lc < 48.f) ? c : ((la <= lc) ? a : c));
      L0 += (ch==0)?1.f:0.f; L1 += (ch==1)?1.f:0.f; L2 += (ch==2)?1.f:0.f; L3 += (ch==3)?1.f:0.f;
      L4 += (ch==4)?1.f:0.f; L5 += (ch==5)?1.f:0.f; L6 += (ch==6)?1.f:0.f; L7 += (ch==7)?1.f:0.f;
      sch[i] = ch;
    }
  }
  __syncthreads();
  const int ch = sch[t];
  chosen[t] = ch;
  #pragma unroll
  for (int e2 = 0; e2 < 8; ++e2) outD[t*8 + e2] = (ch == e2) ? 1.f : 0.f;
}

// ===================== expert pipeline (one block/sample) ==================
// LDS layout (floats), total 16064 (62.75 KB):
#define XP1   0        // pooled1 [32][16][18] (col ofs +1); phase C: swC(4608)/EXCH(8320)
#define XP2   9216     // pooled2 [64][8][10] (col ofs +1); phase A: sx [3][32][34]
#define XSX   9216
#define XW1   12480    // 864
#define XWB   14336    // w2 chunk [2ic][9][64] = 1152
#define XBNS  15488
#define XBNB  15616
#define XFEAT 15744
#define XFF   15872
#define XGG   16000

__global__ __launch_bounds__(256) void expert_kernel(
    const float* __restrict__ x, const int* __restrict__ chosen,
    const float* __restrict__ ew1, const float* __restrict__ eg1, const float* __restrict__ eb1,
    const float* __restrict__ ew2, const float* __restrict__ eg2, const float* __restrict__ eb2,
    const float* __restrict__ ew3, const float* __restrict__ eg3, const float* __restrict__ eb3,
    const float* __restrict__ efw, const float* __restrict__ efb,
    const float* __restrict__ cw1, const float* __restrict__ cb1,
    const float* __restrict__ cw2, const float* __restrict__ cb2,
    float* __restrict__ outF)
{
  __shared__ __align__(16) float sm[16064];
  const int t = threadIdx.x;
  const int b = blockIdx.x;
  const int e = chosen[b];
  const float rs = BN_RS_EXPR;

  // ---- stage phase A: x (padded cols, zeros), w1, bn1, zero P1 borders ----
  for (int j = t; j < 3264; j += 256) {
    int r = j % 1088, xs = r % 34;
    float v = 0.f;
    if (xs >= 1 && xs <= 32) {
      int ic = j / 1088, y = r / 34;
      v = x[b*3072 + ic*1024 + y*32 + xs - 1];
    }
    sm[XSX + j] = v;
  }
  for (int j = t; j < 864; j += 256) sm[XW1 + j] = ew1[e*864 + j];
  if (t < 32) { sm[XBNS + t] = eg1[e*32 + t] * rs; sm[XBNB + t] = eb1[e*32 + t]; }
  for (int j = t; j < 1024; j += 256) {
    int oc = j >> 5, r2 = j & 31, row = r2 >> 1, side = r2 & 1;
    sm[XP1 + oc*288 + row*18 + side*17] = 0.f;
  }
  __syncthreads();

  // ---- phase A: conv1 3->32 (32x32), bn+relu+maxpool -> P1 ----
  for (int m = 0; m < 2; ++m) {
    const int item = m*256 + t;
    const int oc = item >> 4, pr = item & 15;
    float acc[2][32];
    #pragma unroll
    for (int dy = 0; dy < 2; ++dy)
      #pragma unroll
      for (int xx2 = 0; xx2 < 32; ++xx2) acc[dy][xx2] = 0.f;
    for (int ic = 0; ic < 3; ++ic) {
      float w[9];
      #pragma unroll
      for (int k = 0; k < 9; ++k) w[k] = sm[XW1 + oc*27 + ic*9 + k];
      #pragma unroll
      for (int wr = 0; wr < 4; ++wr) {
        const int gr = 2*pr - 1 + wr;
        if (gr < 0 || gr >= 32) continue;  // zero row (conv SAME pad)
        float rv[34];
        const float2* rp = (const float2*)&sm[XSX + ic*1088 + gr*34];
        #pragma unroll
        for (int j2 = 0; j2 < 17; ++j2) { float2 v2 = rp[j2]; rv[2*j2] = v2.x; rv[2*j2+1] = v2.y; }
        #pragma unroll
        for (int dy = 0; dy < 2; ++dy) {
          const int ky = wr - dy;
          if (ky < 0 || ky > 2) continue;
          #pragma unroll
          for (int xx2 = 0; xx2 < 32; ++xx2)
            #pragma unroll
            for (int kx = 0; kx < 3; ++kx)
              acc[dy][xx2] = fmaf(w[ky*3 + kx], rv[xx2 + kx], acc[dy][xx2]);
        }
      }
    }
    const float s = sm[XBNS + oc], bo = sm[XBNB + oc];
    #pragma unroll
    for (int pc = 0; pc < 16; ++pc) {
      float v0 = fmaxf(fmaf(acc[0][2*pc],   s, bo), 0.f);
      float v1 = fmaxf(fmaf(acc[0][2*pc+1], s, bo), 0.f);
      float v2 = fmaxf(fmaf(acc[1][2*pc],   s, bo), 0.f);
      float v3 = fmaxf(fmaf(acc[1][2*pc+1], s, bo), 0.f);
      sm[XP1 + oc*288 + pr*18 + 1 + pc] = fmaxf(fmaxf(v0, v1), fmaxf(v2, v3));
    }
  }
  __syncthreads();

  // ---- phase B prep: bn2, zero P2 borders (sx region is dead now) ----
  if (t < 64) { sm[XBNS + t] = eg2[e*64 + t] * rs; sm[XBNB + t] = eb2[e*64 + t]; }
  for (int j = t; j < 1024; j += 256) {
    int oc = j >> 4, r2 = j & 15, row = r2 >> 1, side = r2 & 1;
    sm[XP2 + oc*80 + row*10 + side*9] = 0.f;
  }

  // ---- phase B: conv2 32->64 (16x16), bn+relu+maxpool -> P2 ----
  {
    const int ocg = t >> 4, pr = (t >> 1) & 7, ch = t & 1;
    float acc[4][2][8];
    #pragma unroll
    for (int o = 0; o < 4; ++o)
      #pragma unroll
      for (int dy = 0; dy < 2; ++dy)
        #pragma unroll
        for (int xx2 = 0; xx2 < 8; ++xx2) acc[o][dy][xx2] = 0.f;
    for (int c = 0; c < 16; ++c) {
      __syncthreads();
      for (int j = t; j < 1152; j += 256) {
        int icl = j / 576, r = j % 576, k = r / 64, oc = r % 64;
        sm[XWB + j] = ew2[e*18432 + oc*288 + (2*c + icl)*9 + k];
      }
      __syncthreads();
      #pragma unroll
      for (int icl = 0; icl < 2; ++icl) {
        const int ic = 2*c + icl;
        float w[4][9];
        #pragma unroll
        for (int k = 0; k < 9; ++k) {
          float4 wv = *(const float4*)&sm[XWB + icl*576 + k*64 + 4*ocg];
          w[0][k] = wv.x; w[1][k] = wv.y; w[2][k] = wv.z; w[3][k] = wv.w;
        }
        #pragma unroll
        for (int wr = 0; wr < 4; ++wr) {
          const int gr = 2*pr - 1 + wr;
          if (gr < 0 || gr >= 16) continue;
          float rv[10];
          const float2* rp = (const float2*)&sm[XP1 + ic*288 + gr*18 + 8*ch];
          #pragma unroll
          for (int j2 = 0; j2 < 5; ++j2) { float2 v2 = rp[j2]; rv[2*j2] = v2.x; rv[2*j2+1] = v2.y; }
          #pragma unroll
          for (int dy = 0; dy < 2; ++dy) {
            const int ky = wr - dy;
            if (ky < 0 || ky > 2) continue;
            #pragma unroll
            for (int xx2 = 0; xx2 < 8; ++xx2)
              #pragma unroll
              for (int kx = 0; kx < 3; ++kx) {
                const float iv = rv[xx2 + kx];
                #pragma unroll
                for (int o = 0; o < 4; ++o)
                  acc[o][dy][xx2] = fmaf(w[o][ky*3 + kx], iv, acc[o][dy][xx2]);
              }
          }
        }
      }
    }
    __syncthreads();
    #pragma unroll
    for (int o = 0; o < 4; ++o) {
      const int oc = 4*ocg + o;
      const float s = sm[XBNS + oc], bo = sm[XBNB + oc];
      #pragma unroll
      for (int pc = 0; pc < 4; ++pc) {
        float v0 = fmaxf(fmaf(acc[o][0][2*pc],   s, bo), 0.f);
        float v1 = fmaxf(fmaf(acc[o][0][2*pc+1], s, bo), 0.f);
        float v2 = fmaxf(fmaf(acc[o][1][2*pc],   s, bo), 0.f);
        float v3 = fmaxf(fmaf(acc[o][1][2*pc+1], s, bo), 0.f);
        sm[XP2 + oc*80 + pr*10 + 1 + 4*ch + pc] = fmaxf(fmaxf(v0, v1), fmaxf(v2, v3));
      }
    }
  }
  __syncthreads();

  // ---- phase C: conv3 64->128 (8x8), bn+relu+GAP -> feat[128] ----
  if (t < 128) { sm[XBNS + t] = eg3[e*128 + t] * rs; sm[XBNB + t] = eb3[e*128 + t]; }
  {
    const int ocg = t >> 3, strip = (t >> 1) & 3, ih = t & 1;
    float acc[4][2][8];
    #pragma unroll
    for (int o = 0; o < 4; ++o)
      #pragma unroll
      for (int dy = 0; dy < 2; ++dy)
        #pragma unroll
        for (int xx2 = 0; xx2 < 8; ++xx2) acc[o][dy][xx2] = 0.f;
    for (int c = 0; c < 16; ++c) {
      __syncthreads();
      for (int j = t; j < 4608; j += 256) {   // swC in P1 region (dead)
        int icl = j / 1152, r = j % 1152, k = r / 128, oc = r % 128;
        int ic = (icl < 2) ? (2*c + icl) : (32 + 2*c + icl - 2);
        sm[XP1 + j] = ew3[e*73728 + oc*576 + ic*9 + k];
      }
      __syncthreads();
      #pragma unroll
      for (int il = 0; il < 2; ++il) {
        const int icl = 2*ih + il;
        const int ic = ih*32 + 2*c + il;
        float w[4][9];
        #pragma unroll
        for (int k = 0; k < 9; ++k) {
          float4 wv = *(const float4*)&sm[XP1 + icl*1152 + k*128 + 4*ocg];
          w[0][k] = wv.x; w[1][k] = wv.y; w[2][k] = wv.z; w[3][k] = wv.w;
        }
        #pragma unroll
        for (int wr = 0; wr < 4; ++wr) {
          const int gr = 2*strip - 1 + wr;
          if (gr < 0 || gr >= 8) continue;
          float rv[10];
          const float2* rp = (const float2*)&sm[XP2 + ic*80 + gr*10];
          #pragma unroll
          for (int j2 = 0; j2 < 5; ++j2) { float2 v2 = rp[j2]; rv[2*j2] = v2.x; rv[2*j2+1] = v2.y; }
          #pragma unroll
          for (int dy = 0; dy < 2; ++dy) {
            const int ky = wr - dy;
            if (ky < 0 || ky > 2) continue;
            #pragma unroll
            for (int xx2 = 0; xx2 < 8; ++xx2)
              #pragma unroll
              for (int kx = 0; kx < 3; ++kx) {
                const float iv = rv[xx2 + kx];
                #pragma unroll
                for (int o = 0; o < 4; ++o)
                  acc[o][dy][xx2] = fmaf(w[o][ky*3 + kx], iv, acc[o][dy][xx2]);
              }
          }
        }
      }
    }
    // combine ic halves (pre-ReLU), then bn+relu+GAP
    __syncthreads();
    const int slot = t >> 1;                  // (ocg*4 + strip), stride 65 pad
    if (ih == 1) {
      #pragma unroll
      for (int o = 0; o < 4; ++o)
        #pragma unroll
        for (int dy = 0; dy < 2; ++dy)
          #pragma unroll
          for (int xx2 = 0; xx2 < 8; ++xx2)
            sm[XP1 + slot*65 + o*16 + dy*8 + xx2] = acc[o][dy][xx2];
    }
    __syncthreads();
    if (ih == 0) {
      #pragma unroll
      for (int o = 0; o < 4; ++o) {
        const int oc = 4*ocg + o;
        const float s = sm[XBNS + oc], bo = sm[XBNB + oc];
        float gp = 0.f;
        #pragma unroll
        for (int dy = 0; dy < 2; ++dy)
          #pragma unroll
          for (int xx2 = 0; xx2 < 8; ++xx2) {
            float v = acc[o][dy][xx2] + sm[XP1 + slot*65 + o*16 + dy*8 + xx2];
            gp += fmaxf(fmaf(v, s, bo), 0.f);
          }
        gp += __shfl_xor(gp, 2);   // even lanes only; partners stay even/active
        gp += __shfl_xor(gp, 4);
        if (strip == 0) sm[XFEAT + oc] = gp * (1.f/64.f);
      }
    }
  }
  __syncthreads();

  // ---- phase D: FC 128->128 relu, 128->64 relu, 64->10 ----
  if (t < 128) {
    float a = efb[e*128 + t];
    const float4* wp = (const float4*)&efw[e*16384 + t*128];
    #pragma unroll 8
    for (int i4 = 0; i4 < 32; ++i4) {
      float4 wv = wp[i4];
      a = fmaf(wv.x, sm[XFEAT + 4*i4],     a);
      a = fmaf(wv.y, sm[XFEAT + 4*i4 + 1], a);
      a = fmaf(wv.z, sm[XFEAT + 4*i4 + 2], a);
      a = fmaf(wv.w, sm[XFEAT + 4*i4 + 3], a);
    }
    sm[XFF + t] = fmaxf(a, 0.f);
  }
  __syncthreads();
  if (t < 64) {
    float a = cb1[e*64 + t];
    const float4* wp = (const float4*)&cw1[e*8192 + t*128];
    #pragma unroll 8
    for (int i4 = 0; i4 < 32; ++i4) {
      float4 wv = wp[i4];
      a = fmaf(wv.x, sm[XFF + 4*i4],     a);
      a = fmaf(wv.y, sm[XFF + 4*i4 + 1], a);
      a = fmaf(wv.z, sm[XFF + 4*i4 + 2], a);
      a = fmaf(wv.w, sm[XFF + 4*i4 + 3], a);
    }
    sm[XGG + t] = fmaxf(a, 0.f);
  }
  __syncthreads();
  if (t < 10) {
    float a = cb2[e*10 + t];
    const float4* wp = (const float4*)&cw2[e*640 + t*64];
    #pragma unroll
    for (int i4 = 0; i4 < 16; ++i4) {
      float4 wv = wp[i4];
      a = fmaf(wv.x, sm[XGG + 4*i4],     a);
      a = fmaf(wv.y, sm[XGG + 4*i4 + 1], a);
      a = fmaf(wv.z, sm[XGG + 4*i4 + 2], a);
      a = fmaf(wv.w, sm[XGG + 4*i4 + 3], a);
    }
    outF[b*10 + t] = a;   // routing weight is exactly 1.0 for the chosen expert
  }
}

// ================================ host =====================================
extern "C" void kernel_launch(void* const* d_in, const int* in_sizes, int n_in,
                              void* d_out, int out_size, void* d_ws, size_t ws_size,
                              hipStream_t stream)
{
  const float* x   = (const float*)d_in[0];
  const float* tw1 = (const float*)d_in[1];
  const float* tg1 = (const float*)d_in[2];
  const float* tb1 = (const float*)d_in[3];
  const float* tw2 = (const float*)d_in[4];
  const float* tg2 = (const float*)d_in[5];
  const float* tb2 = (const float*)d_in[6];
  const float* tfw = (const float*)d_in[7];
  const float* tfb = (const float*)d_in[8];
  const float* gw1 = (const float*)d_in[9];
  const float* gb1 = (const float*)d_in[10];
  const float* gw2 = (const float*)d_in[11];
  const float* gb2 = (const float*)d_in[12];
  const float* ew1 = (const float*)d_in[13];
  const float* eg1 = (const float*)d_in[14];
  const float* eb1 = (const float*)d_in[15];
  const float* ew2 = (const float*)d_in[16];
  const float* eg2 = (const float*)d_in[17];
  const float* eb2 = (const float*)d_in[18];
  const float* ew3 = (const float*)d_in[19];
  const float* eg3 = (const float*)d_in[20];
  const float* eb3 = (const float*)d_in[21];
  const float* efw = (const float*)d_in[22];
  const float* efb = (const float*)d_in[23];
  const float* cw1 = (const float*)d_in[24];
  const float* cb1 = (const float*)d_in[25];
  const float* cw2 = (const float*)d_in[26];
  const float* cb2 = (const float*)d_in[27];

  float* out    = (float*)d_out;                    // final | balanced | D
  float* tf     = (float*)d_ws;                     // [256*128]
  int*   tk     = (int*)((char*)d_ws + 131072);     // [512]
  int*   chosen = tk + 512;                         // [256]

  trunk_kernel<<<1024, 128, 0, stream>>>(x, tw1, tg1, tb1, tw2, tg2, tb2, tf);
  gate_kernel<<<256, 64, 0, stream>>>(tf, tfw, tfb, gw1, gb1, gw2, gb2, out + 2560, tk);
  route_kernel<<<1, 256, 0, stream>>>(tk, chosen, out + 4608);
  expert_kernel<<<256, 256, 0, stream>>>(x, chosen, ew1, eg1, eb1, ew2, eg2, eb2,
                                         ew3, eg3, eb3, efw, efb, cw1, cb1, cw2, cb2, out);
}

// Round 2
// 407.400 us; speedup vs baseline: 1.1180x; 1.1180x over previous
//
#include <hip/hip_runtime.h>
#include <hip/hip_bf16.h>
#include <math.h>

// ---------------------------------------------------------------------------
// DistributedMoE forward, MI355X — R2: occupancy restructure.
// One expert per sample (capacity scan -> single chosen[b]; softmax of one
// element == 1), so experts run only on assigned samples.
// R2 change: split the monolithic per-sample expert kernel (1 block/CU,
// 4 waves) into per-phase kernels with global intermediates; trunk to 256
// threads / 50 KB LDS (3 blocks/CU). Weight staging full-block or
// double-buffered (prefetch overlaps compute, 1 barrier/chunk).
//
// out (fp32): final[256,10] @0, balanced[256,8] @2560, D[256,8] @4608
// ws: tf[256*128] @0 | tk i32[512] @131072 | chosen i32[256] @133120
//     featg[256*128] @134144 | P1g[256][32][16][16] @266240
//     P2g[256][64][8][8] @8654848   (total ~12.9 MB)
// ---------------------------------------------------------------------------

#define BN_RS (1.0f / sqrtf(1.00001f))

// ======================= trunk: conv1+conv2+pool+avg =======================
// grid 1024 = 256 samples x 4 quadrants, 256 threads, LDS 50.3 KB (3 blk/CU)
__global__ __launch_bounds__(256) void trunk_kernel(
    const float* __restrict__ x, const float* __restrict__ tw1,
    const float* __restrict__ tg1, const float* __restrict__ tb1,
    const float* __restrict__ tw2, const float* __restrict__ tg2,
    const float* __restrict__ tb2, float* __restrict__ tf)
{
  __shared__ __align__(16) float sa1[10368];   // conv1 out [32][18][18]
  __shared__ __align__(16) float sw1[864];
  __shared__ __align__(16) float su[1216];     // union: x tile [3][20][20]=1200 | w2 dbuf 2x576
  __shared__ float s1[32], o1[32], s2[32], o2[32];

  const int t = threadIdx.x;
  const int b = blockIdx.x >> 2, q = blockIdx.x & 3;
  const int qy = q >> 1, qx = q & 1;
  const int y0 = qy * 16, x0 = qx * 16;

  for (int j = t; j < 1200; j += 256) {
    int ic = j / 400, r = j % 400, yy = r / 20, xx = r % 20;
    int gy = y0 - 2 + yy, gx = x0 - 2 + xx;
    float v = 0.f;
    if (gy >= 0 && gy < 32 && gx >= 0 && gx < 32) v = x[b*3072 + ic*1024 + gy*32 + gx];
    su[j] = v;
  }
  for (int j = t; j < 864; j += 256) sw1[j] = tw1[j];
  if (t < 32) { s1[t] = tg1[t]*BN_RS; o1[t] = tb1[t]; s2[t] = tg2[t]*BN_RS; o2[t] = tb2[t]; }
  __syncthreads();

  // conv1 -> sa1 (rows r=0..17 ~ quadrant rows -1..16); same math order as R1
  for (int it = 0; it < 3; ++it) {
    const int item = it*256 + t;
    if (item < 576) {
      const int oc = item / 18, r = item % 18;
      const int gy = y0 - 1 + r;
      float acc1[18];
      #pragma unroll
      for (int c2 = 0; c2 < 18; ++c2) acc1[c2] = 0.f;
      if (gy >= 0 && gy < 32) {
        for (int ic = 0; ic < 3; ++ic) {
          float w[9];
          #pragma unroll
          for (int k = 0; k < 9; ++k) w[k] = sw1[oc*27 + ic*9 + k];
          #pragma unroll
          for (int wr = 0; wr < 3; ++wr) {
            float rv[20];
            const float4* rp = (const float4*)&su[ic*400 + (r + wr)*20];
            #pragma unroll
            for (int j4 = 0; j4 < 5; ++j4) {
              float4 v4 = rp[j4];
              rv[4*j4] = v4.x; rv[4*j4+1] = v4.y; rv[4*j4+2] = v4.z; rv[4*j4+3] = v4.w;
            }
            #pragma unroll
            for (int c2 = 0; c2 < 18; ++c2)
              #pragma unroll
              for (int kx = 0; kx < 3; ++kx)
                acc1[c2] = fmaf(w[wr*3 + kx], rv[c2 + kx], acc1[c2]);
          }
        }
      }
      const float s = s1[oc], bo = o1[oc];
      #pragma unroll
      for (int c2 = 0; c2 < 18; ++c2) {
        const int gx = x0 - 1 + c2;
        float v = 0.f;  // out-of-image conv1 acts as conv2 zero pad
        if (gy >= 0 && gy < 32 && gx >= 0 && gx < 32) v = fmaxf(fmaf(acc1[c2], s, bo), 0.f);
        sa1[oc*324 + r*18 + c2] = v;
      }
    }
  }
  __syncthreads();   // conv1 done; su (x tile) now dead -> reuse for w2 chunks

  // preload w2 chunk 0 (ic 0,1) as [icl][9][32oc]
  for (int j = t; j < 576; j += 256) {
    int icl = j/288, r = j%288, k = r/32, oc = r%32;
    su[j] = tw2[oc*288 + icl*9 + k];
  }

  // conv2: thread = (ocg8 x 4oc, pr8 = pooled row, ch4 = 4-col group)
  const int ocg = t >> 5, pr = (t >> 2) & 7, ch = t & 3;
  float acc[4][2][4];
  #pragma unroll
  for (int o = 0; o < 4; ++o)
    #pragma unroll
    for (int dy = 0; dy < 2; ++dy)
      #pragma unroll
      for (int xx = 0; xx < 4; ++xx) acc[o][dy][xx] = 0.f;

  for (int cc = 0; cc < 16; ++cc) {
    __syncthreads();                     // chunk cc visible; other buf free
    if (cc < 15) {                       // prefetch chunk cc+1 (overlaps compute)
      const int buf = (cc + 1) & 1;
      for (int j = t; j < 576; j += 256) {
        int icl = j/288, r = j%288, k = r/32, oc = r%32;
        su[buf*576 + j] = tw2[oc*288 + (2*(cc+1) + icl)*9 + k];
      }
    }
    const float* wb = &su[(cc & 1)*576];
    #pragma unroll
    for (int icl = 0; icl < 2; ++icl) {
      const int ic = 2*cc + icl;
      float w[4][9];
      #pragma unroll
      for (int k = 0; k < 9; ++k) {
        float4 wv = *(const float4*)&wb[icl*288 + k*32 + 4*ocg];
        w[0][k] = wv.x; w[1][k] = wv.y; w[2][k] = wv.z; w[3][k] = wv.w;
      }
      #pragma unroll
      for (int wr = 0; wr < 4; ++wr) {
        float rv[6];
        const float2* rp = (const float2*)&sa1[ic*324 + (2*pr + wr)*18 + 4*ch];
        #pragma unroll
        for (int j2 = 0; j2 < 3; ++j2) { float2 v2 = rp[j2]; rv[2*j2] = v2.x; rv[2*j2+1] = v2.y; }
        #pragma unroll
        for (int dy = 0; dy < 2; ++dy) {
          const int ky = wr - dy;
          if (ky < 0 || ky > 2) continue;
          #pragma unroll
          for (int xx = 0; xx < 4; ++xx)
            #pragma unroll
            for (int kx = 0; kx < 3; ++kx) {
              const float iv = rv[xx + kx];
              #pragma unroll
              for (int o = 0; o < 4; ++o)
                acc[o][dy][xx] = fmaf(w[o][ky*3 + kx], iv, acc[o][dy][xx]);
            }
        }
      }
    }
  }

  // bn + relu + maxpool2 + quadrant mean
  #pragma unroll
  for (int o = 0; o < 4; ++o) {
    const int oc = 4*ocg + o;
    const float s = s2[oc], bo = o2[oc];
    float gp = 0.f;
    #pragma unroll
    for (int pc = 0; pc < 2; ++pc) {
      float v0 = fmaxf(fmaf(acc[o][0][2*pc],   s, bo), 0.f);
      float v1 = fmaxf(fmaf(acc[o][0][2*pc+1], s, bo), 0.f);
      float v2 = fmaxf(fmaf(acc[o][1][2*pc],   s, bo), 0.f);
      float v3 = fmaxf(fmaf(acc[o][1][2*pc+1], s, bo), 0.f);
      gp += fmaxf(fmaxf(v0, v1), fmaxf(v2, v3));
    }
    gp += __shfl_xor(gp, 1);
    gp += __shfl_xor(gp, 2);
    gp += __shfl_xor(gp, 4);
    gp += __shfl_xor(gp, 8);
    gp += __shfl_xor(gp, 16);
    if ((t & 31) == 0) tf[b*128 + oc*4 + qy*2 + qx] = gp * (1.f/64.f);
  }
}

// ============================== gate + top2 ================================
__global__ __launch_bounds__(64) void gate_kernel(
    const float* __restrict__ tf, const float* __restrict__ tfw, const float* __restrict__ tfb,
    const float* __restrict__ gw1, const float* __restrict__ gb1,
    const float* __restrict__ gw2, const float* __restrict__ gb2,
    float* __restrict__ outBal, int* __restrict__ tk)
{
  __shared__ float feat[128], rf[64], g1[32], bal[8];
  const int b = blockIdx.x, t = threadIdx.x;
  feat[t] = tf[b*128 + t];
  feat[64 + t] = tf[b*128 + 64 + t];
  __syncthreads();
  {
    float a = tfb[t];
    const float4* wp = (const float4*)&tfw[t*128];
    #pragma unroll 8
    for (int i4 = 0; i4 < 32; ++i4) {
      float4 wv = wp[i4];
      a = fmaf(wv.x, feat[4*i4], a);   a = fmaf(wv.y, feat[4*i4+1], a);
      a = fmaf(wv.z, feat[4*i4+2], a); a = fmaf(wv.w, feat[4*i4+3], a);
    }
    rf[t] = fmaxf(a, 0.f);
  }
  __syncthreads();
  if (t < 32) {
    float a = gb1[t];
    const float4* wp = (const float4*)&gw1[t*64];
    #pragma unroll
    for (int i4 = 0; i4 < 16; ++i4) {
      float4 wv = wp[i4];
      a = fmaf(wv.x, rf[4*i4], a);   a = fmaf(wv.y, rf[4*i4+1], a);
      a = fmaf(wv.z, rf[4*i4+2], a); a = fmaf(wv.w, rf[4*i4+3], a);
    }
    g1[t] = fmaxf(a, 0.f);
  }
  __syncthreads();
  if (t < 8) {
    float a = gb2[t];
    const float4* wp = (const float4*)&gw2[t*32];
    #pragma unroll
    for (int i4 = 0; i4 < 8; ++i4) {
      float4 wv = wp[i4];
      a = fmaf(wv.x, g1[4*i4], a);   a = fmaf(wv.y, g1[4*i4+1], a);
      a = fmaf(wv.z, g1[4*i4+2], a); a = fmaf(wv.w, g1[4*i4+3], a);
    }
    const float v = a - 0.25f;   // boost=0, -LOAD_PEN*usage = -0.25
    bal[t] = v;
    outBal[b*8 + t] = v;
  }
  __syncthreads();
  if (t == 0) {
    int t0 = 0; float b0 = bal[0];
    #pragma unroll
    for (int e2 = 1; e2 < 8; ++e2) if (bal[e2] > b0) { b0 = bal[e2]; t0 = e2; }
    int t1 = -1; float b1 = -3.4e38f;
    #pragma unroll
    for (int e2 = 0; e2 < 8; ++e2) if (e2 != t0 && bal[e2] > b1) { b1 = bal[e2]; t1 = e2; }
    tk[b*2] = t0; tk[b*2 + 1] = t1;
  }
}

// =================== serial capacity-constrained routing ===================
__global__ __launch_bounds__(256) void route_kernel(const int* __restrict__ tk,
                                                    int* __restrict__ chosen,
                                                    float* __restrict__ outD)
{
  __shared__ int stk[512];
  __shared__ int sch[256];
  const int t = threadIdx.x;
  stk[t] = tk[t]; stk[256 + t] = tk[256 + t];
  __syncthreads();
  if (t == 0) {
    float L0=0,L1=0,L2=0,L3=0,L4=0,L5=0,L6=0,L7=0;
    for (int i = 0; i < 256; ++i) {
      const int a = stk[2*i], c = stk[2*i+1];
      const float la = (a==0)?L0:(a==1)?L1:(a==2)?L2:(a==3)?L3:(a==4)?L4:(a==5)?L5:(a==6)?L6:L7;
      const float lc = (c==0)?L0:(c==1)?L1:(c==2)?L2:(c==3)?L3:(c==4)?L4:(c==5)?L5:(c==6)?L6:L7;
      const int ch = (la < 48.f) ? a : ((lc < 48.f) ? c : ((la <= lc) ? a : c));
      L0 += (ch==0)?1.f:0.f; L1 += (ch==1)?1.f:0.f; L2 += (ch==2)?1.f:0.f; L3 += (ch==3)?1.f:0.f;
      L4 += (ch==4)?1.f:0.f; L5 += (ch==5)?1.f:0.f; L6 += (ch==6)?1.f:0.f; L7 += (ch==7)?1.f:0.f;
      sch[i] = ch;
    }
  }
  __syncthreads();
  const int ch = sch[t];
  chosen[t] = ch;
  #pragma unroll
  for (int e2 = 0; e2 < 8; ++e2) outD[t*8 + e2] = (ch == e2) ? 1.f : 0.f;
}

// ============ expert phase A: conv1 3->32 (32x32) + pool -> P1g ============
// grid 1024 = 256 samples x 4 row-slabs, 128 threads = 32 oc x 4 pooled rows
__global__ __launch_bounds__(128) void expA_kernel(
    const float* __restrict__ x, const int* __restrict__ chosen,
    const float* __restrict__ ew1, const float* __restrict__ eg1,
    const float* __restrict__ eb1, float* __restrict__ P1g)
{
  __shared__ __align__(16) float sxe[1020];  // x slab [3][10][34]
  __shared__ __align__(16) float sw1[864];
  __shared__ float bs[32], bb[32];
  const int t = threadIdx.x;
  const int b = blockIdx.x >> 2, q = blockIdx.x & 3;
  const int r0 = q * 8;                      // conv rows r0..r0+7
  const int e = chosen[b];

  for (int j = t; j < 1020; j += 128) {
    int ic = j / 340, r = (j % 340) / 34, c = j % 34;
    int gy = r0 - 1 + r, gx = c - 1;
    float v = 0.f;
    if (gy >= 0 && gy < 32 && gx >= 0 && gx < 32) v = x[b*3072 + ic*1024 + gy*32 + gx];
    sxe[j] = v;
  }
  for (int j = t; j < 864; j += 128) sw1[j] = ew1[e*864 + j];
  if (t < 32) { bs[t] = eg1[e*32 + t]*BN_RS; bb[t] = eb1[e*32 + t]; }
  __syncthreads();

  const int oc = t >> 2, pr = t & 3;         // pooled row (global q*4+pr)
  float acc[2][32];
  #pragma unroll
  for (int dy = 0; dy < 2; ++dy)
    #pragma unroll
    for (int xx = 0; xx < 32; ++xx) acc[dy][xx] = 0.f;

  for (int ic = 0; ic < 3; ++ic) {
    float w[9];
    #pragma unroll
    for (int k = 0; k < 9; ++k) w[k] = sw1[oc*27 + ic*9 + k];
    #pragma unroll
    for (int wr = 0; wr < 4; ++wr) {
      float rv[34];
      const float2* rp = (const float2*)&sxe[ic*340 + (2*pr + wr)*34];
      #pragma unroll
      for (int j2 = 0; j2 < 17; ++j2) { float2 v2 = rp[j2]; rv[2*j2] = v2.x; rv[2*j2+1] = v2.y; }
      #pragma unroll
      for (int dy = 0; dy < 2; ++dy) {
        const int ky = wr - dy;
        if (ky < 0 || ky > 2) continue;
        #pragma unroll
        for (int xx = 0; xx < 32; ++xx)
          #pragma unroll
          for (int kx = 0; kx < 3; ++kx)
            acc[dy][xx] = fmaf(w[ky*3 + kx], rv[xx + kx], acc[dy][xx]);
      }
    }
  }
  const float s = bs[oc], bo = bb[oc];
  float o16[16];
  #pragma unroll
  for (int pc = 0; pc < 16; ++pc) {
    float v0 = fmaxf(fmaf(acc[0][2*pc],   s, bo), 0.f);
    float v1 = fmaxf(fmaf(acc[0][2*pc+1], s, bo), 0.f);
    float v2 = fmaxf(fmaf(acc[1][2*pc],   s, bo), 0.f);
    float v3 = fmaxf(fmaf(acc[1][2*pc+1], s, bo), 0.f);
    o16[pc] = fmaxf(fmaxf(v0, v1), fmaxf(v2, v3));
  }
  float4* dst = (float4*)&P1g[b*8192 + oc*256 + (q*4 + pr)*16];
  #pragma unroll
  for (int j4 = 0; j4 < 4; ++j4) {
    float4 v; v.x = o16[4*j4]; v.y = o16[4*j4+1]; v.z = o16[4*j4+2]; v.w = o16[4*j4+3];
    dst[j4] = v;
  }
}

// ========= expert phase B: conv2 32->64 (16x16) + pool -> P2g ==============
// grid 512 = 256 samples x 2 oc-halves, 256 thr; full weights staged (1 barrier)
__global__ __launch_bounds__(256) void expB_kernel(
    const int* __restrict__ chosen, const float* __restrict__ P1g,
    const float* __restrict__ ew2, const float* __restrict__ eg2,
    const float* __restrict__ eb2, float* __restrict__ P2g)
{
  __shared__ __align__(16) float sP1[10368];  // padded [32][18][18], data at [+1][+1]
  __shared__ __align__(16) float sW[9216];    // [32ic][9][32oc]
  __shared__ float bs[32], bb[32];
  const int t = threadIdx.x;
  const int b = blockIdx.x >> 1, half = blockIdx.x & 1, oc0 = half*32;
  const int e = chosen[b];

  // zero borders (rows 0,17; cols 0,17)
  for (int j = t; j < 2176; j += 256) {
    int ic = j / 68, rr = j % 68, r, c;
    if (rr < 18)      { r = 0;  c = rr; }
    else if (rr < 36) { r = 17; c = rr - 18; }
    else { int rr2 = rr - 36; r = 1 + (rr2 >> 1); c = (rr2 & 1) * 17; }
    sP1[ic*324 + r*18 + c] = 0.f;
  }
  // fill interior from P1g (coalesced float4 reads)
  const float4* P1g4 = (const float4*)P1g;
  for (int j = t; j < 2048; j += 256) {
    int oc = j >> 6, rem = j & 63, row = rem >> 2, cq = rem & 3;
    float4 v = P1g4[b*2048 + j];
    int base = oc*324 + (row + 1)*18 + 1 + 4*cq;
    sP1[base] = v.x; sP1[base+1] = v.y; sP1[base+2] = v.z; sP1[base+3] = v.w;
  }
  // full weight stage for this half: [ic][k][oc], coalesced global reads
  for (int j = t; j < 9216; j += 256) {
    float v = ew2[e*18432 + oc0*288 + j];
    int oc = j / 288, r = j % 288, ic = r / 9, k = r % 9;
    sW[ic*288 + k*32 + oc] = v;
  }
  if (t < 32) { bs[t] = eg2[e*64 + oc0 + t]*BN_RS; bb[t] = eb2[e*64 + oc0 + t]; }
  __syncthreads();

  const int ocg = t >> 5, pr = (t >> 2) & 7, ch = t & 3;
  float acc[4][2][4];
  #pragma unroll
  for (int o = 0; o < 4; ++o)
    #pragma unroll
    for (int dy = 0; dy < 2; ++dy)
      #pragma unroll
      for (int xx = 0; xx < 4; ++xx) acc[o][dy][xx] = 0.f;

  for (int ic = 0; ic < 32; ++ic) {
    float w[4][9];
    #pragma unroll
    for (int k = 0; k < 9; ++k) {
      float4 wv = *(const float4*)&sW[ic*288 + k*32 + 4*ocg];
      w[0][k] = wv.x; w[1][k] = wv.y; w[2][k] = wv.z; w[3][k] = wv.w;
    }
    #pragma unroll
    for (int wr = 0; wr < 4; ++wr) {
      float rv[6];
      const float2* rp = (const float2*)&sP1[ic*324 + (2*pr + wr)*18 + 4*ch];
      #pragma unroll
      for (int j2 = 0; j2 < 3; ++j2) { float2 v2 = rp[j2]; rv[2*j2] = v2.x; rv[2*j2+1] = v2.y; }
      #pragma unroll
      for (int dy = 0; dy < 2; ++dy) {
        const int ky = wr - dy;
        if (ky < 0 || ky > 2) continue;
        #pragma unroll
        for (int xx = 0; xx < 4; ++xx)
          #pragma unroll
          for (int kx = 0; kx < 3; ++kx) {
            const float iv = rv[xx + kx];
            #pragma unroll
            for (int o = 0; o < 4; ++o)
              acc[o][dy][xx] = fmaf(w[o][ky*3 + kx], iv, acc[o][dy][xx]);
          }
      }
    }
  }

  float2* P2g2 = (float2*)P2g;
  #pragma unroll
  for (int o = 0; o < 4; ++o) {
    const int ocl = 4*ocg + o;
    const float s = bs[ocl], bo = bb[ocl];
    float2 st;
    {
      float v0 = fmaxf(fmaf(acc[o][0][0], s, bo), 0.f);
      float v1 = fmaxf(fmaf(acc[o][0][1], s, bo), 0.f);
      float v2 = fmaxf(fmaf(acc[o][1][0], s, bo), 0.f);
      float v3 = fmaxf(fmaf(acc[o][1][1], s, bo), 0.f);
      st.x = fmaxf(fmaxf(v0, v1), fmaxf(v2, v3));
      v0 = fmaxf(fmaf(acc[o][0][2], s, bo), 0.f);
      v1 = fmaxf(fmaf(acc[o][0][3], s, bo), 0.f);
      v2 = fmaxf(fmaf(acc[o][1][2], s, bo), 0.f);
      v3 = fmaxf(fmaf(acc[o][1][3], s, bo), 0.f);
      st.y = fmaxf(fmaxf(v0, v1), fmaxf(v2, v3));
    }
    P2g2[(b*4096 + (oc0 + ocl)*64 + pr*8 + 2*ch) >> 1] = st;
  }
}

// ====== expert phase C: conv3 64->128 (8x8) + bn/relu + GAP -> featg =======
// grid 512 = 256 x 2 oc-halves, 256 thr; weights double-buffered 8ic chunks
__global__ __launch_bounds__(256) void expC_kernel(
    const int* __restrict__ chosen, const float* __restrict__ P2g,
    const float* __restrict__ ew3, const float* __restrict__ eg3,
    const float* __restrict__ eb3, float* __restrict__ featg)
{
  __shared__ __align__(16) float sP2[6400];     // padded [64][10][10]
  __shared__ __align__(16) float sWc[2][4608];  // chunk [8ic][9][64oc]
  __shared__ float bs[64], bb[64];
  const int t = threadIdx.x;
  const int b = blockIdx.x >> 1, half = blockIdx.x & 1, oc0 = half*64;
  const int e = chosen[b];

  for (int j = t; j < 2304; j += 256) {
    int ic = j / 36, rr = j % 36, r, c;
    if (rr < 10)      { r = 0; c = rr; }
    else if (rr < 20) { r = 9; c = rr - 10; }
    else { int rr2 = rr - 20; r = 1 + (rr2 >> 1); c = (rr2 & 1) * 9; }
    sP2[ic*100 + r*10 + c] = 0.f;
  }
  const float4* P2g4 = (const float4*)P2g;
  for (int j = t; j < 1024; j += 256) {
    int oc = j >> 4, rem = j & 15, row = rem >> 1, cq = rem & 1;
    float4 v = P2g4[b*1024 + j];
    int base = oc*100 + (row + 1)*10 + 1 + 4*cq;
    sP2[base] = v.x; sP2[base+1] = v.y; sP2[base+2] = v.z; sP2[base+3] = v.w;
  }
  if (t < 64) { bs[t] = eg3[e*128 + oc0 + t]*BN_RS; bb[t] = eb3[e*128 + oc0 + t]; }
  // preload weight chunk 0 (ic 0..7)
  for (int j = t; j < 4608; j += 256) {
    int icl = j / 576, r = j % 576, k = r / 64, oc = r % 64;
    sWc[0][j] = ew3[e*73728 + (oc0 + oc)*576 + icl*9 + k];
  }

  const int ocg = t >> 4, strip = (t >> 2) & 3, colq = t & 3;
  float acc[4][2][2];
  #pragma unroll
  for (int o = 0; o < 4; ++o)
    #pragma unroll
    for (int dy = 0; dy < 2; ++dy)
      #pragma unroll
      for (int xx = 0; xx < 2; ++xx) acc[o][dy][xx] = 0.f;

  for (int cc = 0; cc < 8; ++cc) {
    __syncthreads();
    if (cc < 7) {                       // prefetch next chunk into other buffer
      const int buf = (cc + 1) & 1;
      for (int j = t; j < 4608; j += 256) {
        int icl = j / 576, r = j % 576, k = r / 64, oc = r % 64;
        sWc[buf][j] = ew3[e*73728 + (oc0 + oc)*576 + (8*(cc+1) + icl)*9 + k];
      }
    }
    const float* wb = sWc[cc & 1];
    #pragma unroll
    for (int icl = 0; icl < 8; ++icl) {
      const int ic = 8*cc + icl;
      float w[4][9];
      #pragma unroll
      for (int k = 0; k < 9; ++k) {
        float4 wv = *(const float4*)&wb[icl*576 + k*64 + 4*ocg];
        w[0][k] = wv.x; w[1][k] = wv.y; w[2][k] = wv.z; w[3][k] = wv.w;
      }
      #pragma unroll
      for (int wr = 0; wr < 4; ++wr) {
        float rv[4];
        const float2* rp = (const float2*)&sP2[ic*100 + (2*strip + wr)*10 + 2*colq];
        #pragma unroll
        for (int j2 = 0; j2 < 2; ++j2) { float2 v2 = rp[j2]; rv[2*j2] = v2.x; rv[2*j2+1] = v2.y; }
        #pragma unroll
        for (int dy = 0; dy < 2; ++dy) {
          const int ky = wr - dy;
          if (ky < 0 || ky > 2) continue;
          #pragma unroll
          for (int xx = 0; xx < 2; ++xx)
            #pragma unroll
            for (int kx = 0; kx < 3; ++kx) {
              const float iv = rv[xx + kx];
              #pragma unroll
              for (int o = 0; o < 4; ++o)
                acc[o][dy][xx] = fmaf(w[o][ky*3 + kx], iv, acc[o][dy][xx]);
            }
        }
      }
    }
  }

  #pragma unroll
  for (int o = 0; o < 4; ++o) {
    const int ocl = 4*ocg + o;
    const float s = bs[ocl], bo = bb[ocl];
    float g = 0.f;
    #pragma unroll
    for (int dy = 0; dy < 2; ++dy)
      #pragma unroll
      for (int xx = 0; xx < 2; ++xx)
        g += fmaxf(fmaf(acc[o][dy][xx], s, bo), 0.f);
    g += __shfl_xor(g, 1);
    g += __shfl_xor(g, 2);
    g += __shfl_xor(g, 4);
    g += __shfl_xor(g, 8);
    if ((t & 15) == 0) featg[b*128 + oc0 + ocl] = g * (1.f/64.f);
  }
}

// ================= expert phase D: FC chain -> final =======================
__global__ __launch_bounds__(128) void expD_kernel(
    const int* __restrict__ chosen, const float* __restrict__ featg,
    const float* __restrict__ efw, const float* __restrict__ efb,
    const float* __restrict__ cw1, const float* __restrict__ cb1,
    const float* __restrict__ cw2, const float* __restrict__ cb2,
    float* __restrict__ outF)
{
  __shared__ float sf[128], sff[128], sgg[64];
  const int b = blockIdx.x, t = threadIdx.x;
  const int e = chosen[b];
  sf[t] = featg[b*128 + t];
  __syncthreads();
  {
    float a = efb[e*128 + t];
    const float4* wp = (const float4*)&efw[e*16384 + t*128];
    #pragma unroll 8
    for (int i4 = 0; i4 < 32; ++i4) {
      float4 wv = wp[i4];
      a = fmaf(wv.x, sf[4*i4], a);   a = fmaf(wv.y, sf[4*i4+1], a);
      a = fmaf(wv.z, sf[4*i4+2], a); a = fmaf(wv.w, sf[4*i4+3], a);
    }
    sff[t] = fmaxf(a, 0.f);
  }
  __syncthreads();
  if (t < 64) {
    float a = cb1[e*64 + t];
    const float4* wp = (const float4*)&cw1[e*8192 + t*128];
    #pragma unroll 8
    for (int i4 = 0; i4 < 32; ++i4) {
      float4 wv = wp[i4];
      a = fmaf(wv.x, sff[4*i4], a);   a = fmaf(wv.y, sff[4*i4+1], a);
      a = fmaf(wv.z, sff[4*i4+2], a); a = fmaf(wv.w, sff[4*i4+3], a);
    }
    sgg[t] = fmaxf(a, 0.f);
  }
  __syncthreads();
  if (t < 10) {
    float a = cb2[e*10 + t];
    const float4* wp = (const float4*)&cw2[e*640 + t*64];
    #pragma unroll
    for (int i4 = 0; i4 < 16; ++i4) {
      float4 wv = wp[i4];
      a = fmaf(wv.x, sgg[4*i4], a);   a = fmaf(wv.y, sgg[4*i4+1], a);
      a = fmaf(wv.z, sgg[4*i4+2], a); a = fmaf(wv.w, sgg[4*i4+3], a);
    }
    outF[b*10 + t] = a;   // routing weight is exactly 1.0 for the chosen expert
  }
}

// ================================ host =====================================
extern "C" void kernel_launch(void* const* d_in, const int* in_sizes, int n_in,
                              void* d_out, int out_size, void* d_ws, size_t ws_size,
                              hipStream_t stream)
{
  const float* x   = (const float*)d_in[0];
  const float* tw1 = (const float*)d_in[1];
  const float* tg1 = (const float*)d_in[2];
  const float* tb1 = (const float*)d_in[3];
  const float* tw2 = (const float*)d_in[4];
  const float* tg2 = (const float*)d_in[5];
  const float* tb2 = (const float*)d_in[6];
  const float* tfw = (const float*)d_in[7];
  const float* tfb = (const float*)d_in[8];
  const float* gw1 = (const float*)d_in[9];
  const float* gb1 = (const float*)d_in[10];
  const float* gw2 = (const float*)d_in[11];
  const float* gb2 = (const float*)d_in[12];
  const float* ew1 = (const float*)d_in[13];
  const float* eg1 = (const float*)d_in[14];
  const float* eb1 = (const float*)d_in[15];
  const float* ew2 = (const float*)d_in[16];
  const float* eg2 = (const float*)d_in[17];
  const float* eb2 = (const float*)d_in[18];
  const float* ew3 = (const float*)d_in[19];
  const float* eg3 = (const float*)d_in[20];
  const float* eb3 = (const float*)d_in[21];
  const float* efw = (const float*)d_in[22];
  const float* efb = (const float*)d_in[23];
  const float* cw1 = (const float*)d_in[24];
  const float* cb1 = (const float*)d_in[25];
  const float* cw2 = (const float*)d_in[26];
  const float* cb2 = (const float*)d_in[27];

  float* out    = (float*)d_out;                      // final | balanced | D
  float* tf     = (float*)d_ws;                       // 131072 B
  int*   tk     = (int*)((char*)d_ws + 131072);       // 2048 B
  int*   chosen = (int*)((char*)d_ws + 133120);       // 1024 B
  float* featg  = (float*)((char*)d_ws + 134144);     // 131072 B
  float* P1g    = (float*)((char*)d_ws + 266240);     // 8388608 B
  float* P2g    = (float*)((char*)d_ws + 8654848);    // 4194304 B

  trunk_kernel<<<1024, 256, 0, stream>>>(x, tw1, tg1, tb1, tw2, tg2, tb2, tf);
  gate_kernel<<<256, 64, 0, stream>>>(tf, tfw, tfb, gw1, gb1, gw2, gb2, out + 2560, tk);
  route_kernel<<<1, 256, 0, stream>>>(tk, chosen, out + 4608);
  expA_kernel<<<1024, 128, 0, stream>>>(x, chosen, ew1, eg1, eb1, P1g);
  expB_kernel<<<512, 256, 0, stream>>>(chosen, P1g, ew2, eg2, eb2, P2g);
  expC_kernel<<<512, 256, 0, stream>>>(chosen, P2g, ew3, eg3, eb3, featg);
  expD_kernel<<<256, 128, 0, stream>>>(chosen, featg, efw, efb, cw1, cb1, cw2, cb2, out);
}